// Round 1
// baseline (348.978 us; speedup 1.0000x reference)
//
#include <hip/hip_runtime.h>
#include <hip/hip_bf16.h>

#define NT 65536   // text rows (M)
#define NL 1024    // label rows (N)
#define DD 256     // feature dim (K)

#define BM 128
#define BN 128
#define BK 64

typedef __attribute__((ext_vector_type(4))) float f32x4;
typedef __attribute__((ext_vector_type(8))) short bf16x8;

__device__ inline short f2bf(float x) {
    union { __hip_bfloat16 b; short s; } u;
    u.b = __float2bfloat16(x);   // RNE
    return u.s;
}

// ---------------- norms: one wave per row, reciprocal norm to ws ----------
__global__ __launch_bounds__(256) void norms_k(const float* __restrict__ A,
                                               const float* __restrict__ Bm,
                                               float* __restrict__ rt,
                                               float* __restrict__ rl) {
    int gw   = (blockIdx.x * 256 + threadIdx.x) >> 6;  // global wave id = row
    int lane = threadIdx.x & 63;
    if (gw >= NT + NL) return;
    const float* src = (gw < NT) ? (A + (size_t)gw * DD)
                                 : (Bm + (size_t)(gw - NT) * DD);
    float4 v = reinterpret_cast<const float4*>(src)[lane];  // 64 lanes x 4 = 256
    float s = v.x * v.x + v.y * v.y + v.z * v.z + v.w * v.w;
#pragma unroll
    for (int off = 32; off > 0; off >>= 1) s += __shfl_xor(s, off);
    if (lane == 0) {
        float n = sqrtf(s);
        float r = 1.0f / fmaxf(n, 1e-20f);  // eps (1e-8 on n*n') never binds for gaussian rows
        if (gw < NT) rt[gw] = r; else rl[gw - NT] = r;
    }
}

// ---------------- fused cosine-sim GEMM ----------------------------------
// C[m][l] = dot(A[m], B[l]) * rt[m] * rl[l]
// 128x128 tile, BK=64, 4 waves (2x2 of 64x64), mfma_f32_16x16x32_bf16.
// fp32->bf16 conversion inline during staging (register staged).
__global__ __launch_bounds__(256, 2) void cosim_k(const float* __restrict__ A,
                                                  const float* __restrict__ Bm,
                                                  const float* __restrict__ rt,
                                                  const float* __restrict__ rl,
                                                  float* __restrict__ C) {
    __shared__ short As[BM * BK];
    __shared__ short Bs[BN * BK];

    const int tid  = threadIdx.x;
    const int lane = tid & 63;
    const int wid  = tid >> 6;       // 0..3
    const int wr   = wid >> 1;       // wave row 0..1
    const int wc   = wid & 1;        // wave col 0..1

    // XCD-aware swizzle: 4096 blocks, 8 XCDs -> each XCD owns a contiguous
    // 64-tile-row M range so A-tiles are reused within one private L2.
    const int orig = blockIdx.x;
    const int id   = (orig & 7) * (4096 / 8) + (orig >> 3);
    const int bx   = id & 7;         // N tile (8 of them)
    const int by   = id >> 3;        // M tile (512 of them)

    const int m0 = by * BM;
    const int l0 = bx * BN;

    // staging: 128x64 fp32 tile = 2048 float4; 256 threads x 8 float4 each
    const int srow = tid >> 4;       // 0..15, +i*16
    const int sc4  = tid & 15;       // float4 column within 64-float row chunk

    f32x4 ra[8], rb[8];

    auto loadg = [&](int kt) {
        const float* pa = A  + (size_t)m0 * DD + kt * BK;
        const float* pb = Bm + (size_t)l0 * DD + kt * BK;
#pragma unroll
        for (int i = 0; i < 8; ++i) {
            int row = srow + i * 16;
            ra[i] = reinterpret_cast<const f32x4*>(pa + (size_t)row * DD)[sc4];
            rb[i] = reinterpret_cast<const f32x4*>(pb + (size_t)row * DD)[sc4];
        }
    };

    auto stash = [&]() {
#pragma unroll
        for (int i = 0; i < 8; ++i) {
            int row = srow + i * 16;
            short4 pa, pb;
            pa.x = f2bf(ra[i].x); pa.y = f2bf(ra[i].y);
            pa.z = f2bf(ra[i].z); pa.w = f2bf(ra[i].w);
            pb.x = f2bf(rb[i].x); pb.y = f2bf(rb[i].y);
            pb.z = f2bf(rb[i].z); pb.w = f2bf(rb[i].w);
            *reinterpret_cast<short4*>(&As[row * BK + sc4 * 4]) = pa;
            *reinterpret_cast<short4*>(&Bs[row * BK + sc4 * 4]) = pb;
        }
    };

    f32x4 acc[4][4] = {};

    loadg(0);
#pragma unroll
    for (int kt = 0; kt < DD / BK; ++kt) {
        __syncthreads();             // previous compute done, LDS free
        stash();
        __syncthreads();
        if (kt < DD / BK - 1) loadg(kt + 1);   // prefetch under compute
#pragma unroll
        for (int ks = 0; ks < 2; ++ks) {       // two K=32 slices per BK=64
            bf16x8 af[4], bfr[4];
            const int kof = ks * 32 + (lane >> 4) * 8;
            const int ar  = wr * 64 + (lane & 15);
            const int bc  = wc * 64 + (lane & 15);
#pragma unroll
            for (int i = 0; i < 4; ++i)
                af[i] = *reinterpret_cast<const bf16x8*>(&As[(ar + i * 16) * BK + kof]);
#pragma unroll
            for (int j = 0; j < 4; ++j)
                bfr[j] = *reinterpret_cast<const bf16x8*>(&Bs[(bc + j * 16) * BK + kof]);
#pragma unroll
            for (int i = 0; i < 4; ++i)
#pragma unroll
                for (int j = 0; j < 4; ++j)
                    acc[i][j] = __builtin_amdgcn_mfma_f32_16x16x32_bf16(
                        af[i], bfr[j], acc[i][j], 0, 0, 0);
        }
    }

    // epilogue: C/D layout col=lane&15, row=(lane>>4)*4+reg
    const int crow0 = m0 + wr * 64;
    const int ccol0 = l0 + wc * 64;
    const int rq = lane >> 4;
    const int cc = lane & 15;
#pragma unroll
    for (int i = 0; i < 4; ++i) {
#pragma unroll
        for (int r = 0; r < 4; ++r) {
            int row = crow0 + i * 16 + rq * 4 + r;
            float rsc = rt[row];
            float* crow = C + (size_t)row * NL;
#pragma unroll
            for (int j = 0; j < 4; ++j) {
                int col = ccol0 + j * 16 + cc;
                crow[col] = acc[i][j][r] * rsc * rl[col];
            }
        }
    }
}

extern "C" void kernel_launch(void* const* d_in, const int* in_sizes, int n_in,
                              void* d_out, int out_size, void* d_ws, size_t ws_size,
                              hipStream_t stream) {
    const float* A  = (const float*)d_in[0];   // [65536,256] fp32
    const float* Bm = (const float*)d_in[1];   // [1024,256]  fp32
    float* C  = (float*)d_out;                 // [65536,1024] fp32
    float* rt = (float*)d_ws;                  // 65536 reciprocal text norms
    float* rl = rt + NT;                       // 1024 reciprocal label norms

    norms_k<<<(NT + NL) / 4, 256, 0, stream>>>(A, Bm, rt, rl);

    dim3 grid(NL / BN * NT / BM);              // 4096 blocks, 1D for swizzle
    cosim_k<<<grid, 256, 0, stream>>>(A, Bm, rt, rl, C);
}

// Round 5
// 340.112 us; speedup vs baseline: 1.0261x; 1.0261x over previous
//
#include <hip/hip_runtime.h>
#include <hip/hip_bf16.h>

#define NT 65536   // text rows (M)
#define NL 1024    // label rows (N)
#define DD 256     // feature dim (K)

#define BM 128
#define BN 128
#define BK 64

typedef __attribute__((ext_vector_type(4))) float f32x4;
typedef __attribute__((ext_vector_type(8))) short bf16x8;

__device__ inline short f2bf(float x) {
    union { __hip_bfloat16 b; short s; } u;
    u.b = __float2bfloat16(x);   // RNE
    return u.s;
}

__device__ inline void gload_lds16(const void* g, void* l) {
    __builtin_amdgcn_global_load_lds((const __attribute__((address_space(1))) void*)g,
                                     (__attribute__((address_space(3))) void*)l,
                                     16, 0, 0);
}

// ---------------- prep: bf16 conversion + reciprocal norms ----------------
// One wave per row (256 floats = 64 lanes x float4). Writes bf16 row (512 B,
// coalesced short4) and 1/max(norm,eps).
__global__ __launch_bounds__(256) void prep_k(const float* __restrict__ A,
                                              const float* __restrict__ Bm,
                                              short* __restrict__ Abf,
                                              short* __restrict__ Bbf,
                                              float* __restrict__ rt,
                                              float* __restrict__ rl) {
    int gw   = (blockIdx.x * 256 + threadIdx.x) >> 6;
    int lane = threadIdx.x & 63;
    if (gw >= NT + NL) return;
    const float* src = (gw < NT) ? (A + (size_t)gw * DD) : (Bm + (size_t)(gw - NT) * DD);
    short*       dst = (gw < NT) ? (Abf + (size_t)gw * DD) : (Bbf + (size_t)(gw - NT) * DD);
    float4 v = reinterpret_cast<const float4*>(src)[lane];
    short4 o;
    o.x = f2bf(v.x); o.y = f2bf(v.y); o.z = f2bf(v.z); o.w = f2bf(v.w);
    reinterpret_cast<short4*>(dst)[lane] = o;
    float s = v.x * v.x + v.y * v.y + v.z * v.z + v.w * v.w;
#pragma unroll
    for (int off = 32; off > 0; off >>= 1) s += __shfl_xor(s, off);
    if (lane == 0) {
        float r = 1.0f / fmaxf(sqrtf(s), 1e-20f);
        if (gw < NT) rt[gw] = r; else rl[gw - NT] = r;
    }
}

// ---------------- bf16 cosine-sim GEMM (m97 structure) --------------------
// C[m][l] = dot(Abf[m], Bbf[l]) * rt[m] * rl[l]
// 128x128 tile, BK=64, 4 waves (2x2 of 64x64), mfma_f32_16x16x32_bf16.
// Staging: global_load_lds width=16, LDS linear, XOR-swizzle applied by
// permuting the per-lane GLOBAL source chunk (m173); reads deswizzle.
__global__ __launch_bounds__(256, 3) void cosim_bf_k(const short* __restrict__ Abf,
                                                     const short* __restrict__ Bbf,
                                                     const float* __restrict__ rt,
                                                     const float* __restrict__ rl,
                                                     float* __restrict__ C) {
    __shared__ short As[BM * BK];   // 16 KB, row = 64 shorts = 128 B
    __shared__ short Bs[BN * BK];   // 16 KB

    const int tid  = threadIdx.x;
    const int lane = tid & 63;
    const int w    = tid >> 6;       // 0..3
    const int wr   = w >> 1;         // wave row
    const int wc   = w & 1;          // wave col

    // XCD-aware swizzle: each XCD owns a contiguous M range -> A-tile L2 reuse
    const int orig = blockIdx.x;
    const int id   = (orig & 7) * (4096 / 8) + (orig >> 3);
    const int bx   = id & 7;         // N tile
    const int by   = id >> 3;        // M tile
    const int m0   = by * BM;
    const int l0   = bx * BN;

    // staging decomposition: one gload_lds16 = 64 lanes x 16B = 8 rows x 8 chunks
    const int l8 = lane >> 3;        // row within 8-row group (== row&7)
    const int ch = lane & 7;         // dest chunk (LDS is linear in lane order)
    const int cg = ch ^ l8;          // swizzled SOURCE chunk: slot(r,c) <- global chunk c^(r&7)

    f32x4 acc[4][4] = {};

#pragma unroll
    for (int kt = 0; kt < DD / BK; ++kt) {
        __syncthreads();             // LDS free (prev compute done)
#pragma unroll
        for (int i = 0; i < 4; ++i) {
            int r = w * 32 + i * 8 + l8;   // row within tile; r&7 == l8
            gload_lds16(Abf + (size_t)(m0 + r) * DD + kt * BK + cg * 8,
                        &As[(w * 32 + i * 8) * BK]);
            gload_lds16(Bbf + (size_t)(l0 + r) * DD + kt * BK + cg * 8,
                        &Bs[(w * 32 + i * 8) * BK]);
        }
        __syncthreads();             // drains vmcnt -> tiles ready
#pragma unroll
        for (int ks = 0; ks < 2; ++ks) {
            bf16x8 af[4], bfr[4];
            const int fr = lane & 15;
            const int fq = lane >> 4;
#pragma unroll
            for (int i = 0; i < 4; ++i) {
                int row = wr * 64 + i * 16 + fr;
                int ck  = (ks * 4 + fq) ^ (row & 7);   // deswizzle
                af[i] = *reinterpret_cast<const bf16x8*>(&As[row * BK + ck * 8]);
            }
#pragma unroll
            for (int j = 0; j < 4; ++j) {
                int row = wc * 64 + j * 16 + fr;
                int ck  = (ks * 4 + fq) ^ (row & 7);
                bfr[j] = *reinterpret_cast<const bf16x8*>(&Bs[row * BK + ck * 8]);
            }
#pragma unroll
            for (int i = 0; i < 4; ++i)
#pragma unroll
                for (int j = 0; j < 4; ++j)
                    acc[i][j] = __builtin_amdgcn_mfma_f32_16x16x32_bf16(
                        af[i], bfr[j], acc[i][j], 0, 0, 0);
        }
    }

    // epilogue: C/D layout col=lane&15, row=(lane>>4)*4+reg
    const int crow0 = m0 + wr * 64;
    const int ccol0 = l0 + wc * 64;
    const int rq = lane >> 4;
    const int cc = lane & 15;
#pragma unroll
    for (int i = 0; i < 4; ++i) {
#pragma unroll
        for (int r = 0; r < 4; ++r) {
            int row = crow0 + i * 16 + rq * 4 + r;
            float rsc = rt[row];
            float* crow = C + (size_t)row * NL;
#pragma unroll
            for (int j = 0; j < 4; ++j) {
                int col = ccol0 + j * 16 + cc;
                crow[col] = acc[i][j][r] * rsc * rl[col];
            }
        }
    }
}

// ---------------- fallback (round-1 fused path, ws < 34 MB) ---------------
__global__ __launch_bounds__(256) void norms_k(const float* __restrict__ A,
                                               const float* __restrict__ Bm,
                                               float* __restrict__ rt,
                                               float* __restrict__ rl) {
    int gw   = (blockIdx.x * 256 + threadIdx.x) >> 6;
    int lane = threadIdx.x & 63;
    if (gw >= NT + NL) return;
    const float* src = (gw < NT) ? (A + (size_t)gw * DD) : (Bm + (size_t)(gw - NT) * DD);
    float4 v = reinterpret_cast<const float4*>(src)[lane];
    float s = v.x * v.x + v.y * v.y + v.z * v.z + v.w * v.w;
#pragma unroll
    for (int off = 32; off > 0; off >>= 1) s += __shfl_xor(s, off);
    if (lane == 0) {
        float r = 1.0f / fmaxf(sqrtf(s), 1e-20f);
        if (gw < NT) rt[gw] = r; else rl[gw - NT] = r;
    }
}

__global__ __launch_bounds__(256, 2) void cosim_fused_k(const float* __restrict__ A,
                                                        const float* __restrict__ Bm,
                                                        const float* __restrict__ rt,
                                                        const float* __restrict__ rl,
                                                        float* __restrict__ C) {
    __shared__ short As[BM * BK];
    __shared__ short Bs[BN * BK];
    const int tid  = threadIdx.x;
    const int lane = tid & 63;
    const int wid  = tid >> 6;
    const int wr   = wid >> 1;
    const int wc   = wid & 1;
    const int orig = blockIdx.x;
    const int id   = (orig & 7) * (4096 / 8) + (orig >> 3);
    const int bx   = id & 7;
    const int by   = id >> 3;
    const int m0 = by * BM;
    const int l0 = bx * BN;
    const int srow = tid >> 4;
    const int sc4  = tid & 15;
    f32x4 ra[8], rb[8];
    auto loadg = [&](int kt) {
        const float* pa = A  + (size_t)m0 * DD + kt * BK;
        const float* pb = Bm + (size_t)l0 * DD + kt * BK;
#pragma unroll
        for (int i = 0; i < 8; ++i) {
            int row = srow + i * 16;
            ra[i] = reinterpret_cast<const f32x4*>(pa + (size_t)row * DD)[sc4];
            rb[i] = reinterpret_cast<const f32x4*>(pb + (size_t)row * DD)[sc4];
        }
    };
    auto stash = [&]() {
#pragma unroll
        for (int i = 0; i < 8; ++i) {
            int row = srow + i * 16;
            short4 pa, pb;
            pa.x = f2bf(ra[i].x); pa.y = f2bf(ra[i].y);
            pa.z = f2bf(ra[i].z); pa.w = f2bf(ra[i].w);
            pb.x = f2bf(rb[i].x); pb.y = f2bf(rb[i].y);
            pb.z = f2bf(rb[i].z); pb.w = f2bf(rb[i].w);
            *reinterpret_cast<short4*>(&As[row * BK + sc4 * 4]) = pa;
            *reinterpret_cast<short4*>(&Bs[row * BK + sc4 * 4]) = pb;
        }
    };
    f32x4 acc[4][4] = {};
    loadg(0);
#pragma unroll
    for (int kt = 0; kt < DD / BK; ++kt) {
        __syncthreads();
        stash();
        __syncthreads();
        if (kt < DD / BK - 1) loadg(kt + 1);
#pragma unroll
        for (int ks = 0; ks < 2; ++ks) {
            bf16x8 af[4], bfr[4];
            const int kof = ks * 32 + (lane >> 4) * 8;
            const int ar  = wr * 64 + (lane & 15);
            const int bc  = wc * 64 + (lane & 15);
#pragma unroll
            for (int i = 0; i < 4; ++i)
                af[i] = *reinterpret_cast<const bf16x8*>(&As[(ar + i * 16) * BK + kof]);
#pragma unroll
            for (int j = 0; j < 4; ++j)
                bfr[j] = *reinterpret_cast<const bf16x8*>(&Bs[(bc + j * 16) * BK + kof]);
#pragma unroll
            for (int i = 0; i < 4; ++i)
#pragma unroll
                for (int j = 0; j < 4; ++j)
                    acc[i][j] = __builtin_amdgcn_mfma_f32_16x16x32_bf16(
                        af[i], bfr[j], acc[i][j], 0, 0, 0);
        }
    }
    const int crow0 = m0 + wr * 64;
    const int ccol0 = l0 + wc * 64;
    const int rq = lane >> 4;
    const int cc = lane & 15;
#pragma unroll
    for (int i = 0; i < 4; ++i) {
#pragma unroll
        for (int r = 0; r < 4; ++r) {
            int row = crow0 + i * 16 + rq * 4 + r;
            float rsc = rt[row];
            float* crow = C + (size_t)row * NL;
#pragma unroll
            for (int j = 0; j < 4; ++j) {
                int col = ccol0 + j * 16 + cc;
                crow[col] = acc[i][j][r] * rsc * rl[col];
            }
        }
    }
}

extern "C" void kernel_launch(void* const* d_in, const int* in_sizes, int n_in,
                              void* d_out, int out_size, void* d_ws, size_t ws_size,
                              hipStream_t stream) {
    const float* A  = (const float*)d_in[0];   // [65536,256] fp32
    const float* Bm = (const float*)d_in[1];   // [1024,256]  fp32
    float* C = (float*)d_out;                  // [65536,1024] fp32

    const size_t abf_elems = (size_t)NT * DD;          // 33.5 M shorts
    const size_t bbf_elems = (size_t)NL * DD;
    const size_t need = (abf_elems + bbf_elems) * sizeof(short)
                      + (NT + NL) * sizeof(float);

    if (ws_size >= need) {
        short* Abf = (short*)d_ws;
        short* Bbf = Abf + abf_elems;
        float* rt  = (float*)(Bbf + bbf_elems);
        float* rl  = rt + NT;
        prep_k<<<(NT + NL) / 4, 256, 0, stream>>>(A, Bm, Abf, Bbf, rt, rl);
        cosim_bf_k<<<(NL / BN) * (NT / BM), 256, 0, stream>>>(Abf, Bbf, rt, rl, C);
    } else {
        float* rt = (float*)d_ws;
        float* rl = rt + NT;
        norms_k<<<(NT + NL) / 4, 256, 0, stream>>>(A, Bm, rt, rl);
        cosim_fused_k<<<(NL / BN) * (NT / BM), 256, 0, stream>>>(A, Bm, rt, rl, C);
    }
}